// Round 15
// baseline (1393.205 us; speedup 1.0000x reference)
//
#include <hip/hip_runtime.h>
#include <hip/hip_bf16.h>

// GCNEncoder — PASSING (absmax .0039; r14 dur 1390us). Correct omega:
// partitionable threefry (counter (0,i), bits = o0^o1), f64 erfinv.
// r15 perf: cholinv still 245us/call — the LDS read-modify-write latency
// chain in the trailing update dominates (not int-div as r14 theorized).
// Rewrite: REGISTER-RESIDENT Cholesky. Thread t owns column j=t&63 at rows
// i=4q+(t>>6) in registers; per step, column k is published to a 64-entry
// LDS buffer and the trailing update is independent register FMAs. L dumped
// to LDS once for the wave-per-column back-substitution (multiply-only).

#define NN    4096
#define NEDG  131072
#define INC   512
#define HIDC  512
#define OUTC  64
#define RK    64
#define NDOM  4
#define EPSBN 1e-5f

static inline int cdiv(int a, int b){ return (a + b - 1) / b; }

// ---------------- input dtype detection (f32 vs bf16 carriers) ----------------
__global__ __launch_bounds__(256) void k_detect(const unsigned short* __restrict__ p,
                                                int* __restrict__ flag){
  int t = threadIdx.x;
  int cnt = 0;
  for (int i = t; i < 4096; i += 256){
    unsigned short v = p[2*i];
    int e = (v >> 7) & 0xFF;
    if (e >= 100 && e <= 140) cnt++;
  }
  __shared__ int sh[256];
  sh[t] = cnt; __syncthreads();
  for (int off = 128; off > 0; off >>= 1){ if (t < off) sh[t] += sh[t+off]; __syncthreads(); }
  if (t == 0) *flag = (sh[0] >= 2048) ? 0 : 1;
}

// ---------------- elementwise utils ----------------
__global__ __launch_bounds__(256) void k_upcast(const void* __restrict__ s,
                                                const int* __restrict__ isf32,
                                                float* __restrict__ d, int n){
  int i = blockIdx.x*256 + threadIdx.x;
  if (i >= n) return;
  if (*isf32) d[i] = ((const float*)s)[i];
  else        d[i] = __bfloat162float(((const __hip_bfloat16*)s)[i]);
}
__global__ __launch_bounds__(256) void k_fill(float* d, float v, int n){
  int i = blockIdx.x*256 + threadIdx.x;
  if (i < n) d[i] = v;
}
__global__ __launch_bounds__(256) void k_filli(int* d, int v, int n){
  int i = blockIdx.x*256 + threadIdx.x;
  if (i < n) d[i] = v;
}
__global__ __launch_bounds__(256) void k_filld(double* d, double v, int n){
  int i = blockIdx.x*256 + threadIdx.x;
  if (i < n) d[i] = v;
}
__global__ __launch_bounds__(256) void k_copy(const float* __restrict__ z,
                                              float* __restrict__ o, int n){
  int i = blockIdx.x*256 + threadIdx.x;
  if (i < n) o[i] = z[i];
}
__global__ __launch_bounds__(256) void k_f32to64(const float* __restrict__ s,
                                                 double* __restrict__ d, int n){
  int i = blockIdx.x*256 + threadIdx.x;
  if (i < n) d[i] = (double)s[i];
}
__global__ __launch_bounds__(256) void k_f64to32(const double* __restrict__ s,
                                                 float* __restrict__ d, int n){
  int i = blockIdx.x*256 + threadIdx.x;
  if (i < n) d[i] = (float)s[i];
}

// ---------------- graph preprocessing ----------------
__global__ __launch_bounds__(256) void k_hist(const int* __restrict__ row, const int* __restrict__ col,
                                              const float* __restrict__ w, float* deg,
                                              int* cntR, int* cntC){
  int e = blockIdx.x*256 + threadIdx.x;
  if (e < NEDG){
    atomicAdd(&deg[col[e]], w[e]);
    atomicAdd(&cntR[row[e]], 1);
    atomicAdd(&cntC[col[e]], 1);
  }
}
__global__ __launch_bounds__(256) void k_dinv(const float* deg, float* dinv, int n){
  int i = blockIdx.x*256 + threadIdx.x;
  if (i < n){ float d = deg[i]; dinv[i] = (d > 0.f) ? 1.f/sqrtf(d) : 0.f; }
}
__global__ __launch_bounds__(256) void k_norm1(const int* __restrict__ row, const int* __restrict__ col,
                                               const float* __restrict__ w, const float* __restrict__ dinv,
                                               float* __restrict__ nrm){
  int e = blockIdx.x*256 + threadIdx.x;
  if (e < NEDG) nrm[e] = dinv[row[e]] * w[e] * dinv[col[e]];
}
__global__ __launch_bounds__(1024) void k_scan4096(const int* __restrict__ cnt,
                                                   int* __restrict__ ptr, int* __restrict__ pos){
  __shared__ int sh[1024];
  int t = threadIdx.x;
  int b = t*4;
  int a0 = cnt[b], a1 = cnt[b+1], a2 = cnt[b+2], a3 = cnt[b+3];
  sh[t] = a0 + a1 + a2 + a3;
  __syncthreads();
  for (int off = 1; off < 1024; off <<= 1){
    int v = (t >= off) ? sh[t-off] : 0;
    __syncthreads();
    sh[t] += v;
    __syncthreads();
  }
  int excl = (t == 0) ? 0 : sh[t-1];
  ptr[b]   = excl;            pos[b]   = excl;
  ptr[b+1] = excl+a0;         pos[b+1] = excl+a0;
  ptr[b+2] = excl+a0+a1;      pos[b+2] = excl+a0+a1;
  ptr[b+3] = excl+a0+a1+a2;   pos[b+3] = excl+a0+a1+a2;
  if (t == 1023) ptr[4096] = sh[1023];
}
__global__ __launch_bounds__(256) void k_scatter(const int* __restrict__ row, const int* __restrict__ col,
                                                 int* posR, int* posC, int* eidR, int* eidC){
  int e = blockIdx.x*256 + threadIdx.x;
  if (e < NEDG){
    int p = atomicAdd(&posR[row[e]], 1); eidR[p] = e;
    int q = atomicAdd(&posC[col[e]], 1); eidC[q] = e;
  }
}
__global__ __launch_bounds__(256) void k_dcnt(const int* __restrict__ y, int* dcnt){
  int i = blockIdx.x*256 + threadIdx.x;
  if (i < NN) atomicAdd(&dcnt[y[i]], 1);
}

// ---------------- threefry2x32 core (KAT-verified round 8) ----------------
__device__ __forceinline__ unsigned rotl32(unsigned x, unsigned d){ return (x << d) | (x >> (32u - d)); }
#define TF_ROUND4(R0,R1,R2,R3) \
  x0 += x1; x1 = rotl32(x1,R0); x1 ^= x0; \
  x0 += x1; x1 = rotl32(x1,R1); x1 ^= x0; \
  x0 += x1; x1 = rotl32(x1,R2); x1 ^= x0; \
  x0 += x1; x1 = rotl32(x1,R3); x1 ^= x0;

__device__ __forceinline__ void tf2x32(unsigned k0, unsigned k1, unsigned c0, unsigned c1,
                                       unsigned* o0, unsigned* o1){
  unsigned ks2 = 0x1BD11BDAu ^ k0 ^ k1;
  unsigned x0 = c0 + k0, x1 = c1 + k1;
  TF_ROUND4(13,15,26,6);   x0 += k1;  x1 += ks2 + 1u;
  TF_ROUND4(17,29,16,24);  x0 += ks2; x1 += k0 + 2u;
  TF_ROUND4(13,15,26,6);   x0 += k0;  x1 += k1 + 3u;
  TF_ROUND4(17,29,16,24);  x0 += k1;  x1 += ks2 + 4u;
  TF_ROUND4(13,15,26,6);   x0 += ks2; x1 += k0 + 5u;
  *o0 = x0; *o1 = x1;
}

// ---------------- omega (verified round 10) ----------------
__device__ double erfinv64(double x){
  double w = -log1p(-x*x);
  double p;
  if (w < 5.0){
    w -= 2.5;
    p = 2.81022636e-08;  p = p*w + 3.43273939e-07; p = p*w - 3.5233877e-06;
    p = p*w - 4.39150654e-06; p = p*w + 0.00021858087; p = p*w - 0.00125372503;
    p = p*w - 0.00417768164;  p = p*w + 0.246640727;   p = p*w + 1.50140941;
  } else {
    w = sqrt(w) - 3.0;
    p = -0.000200214257; p = p*w + 0.000100950558; p = p*w + 0.00134934322;
    p = p*w - 0.00367342844; p = p*w + 0.00573950773; p = p*w - 0.0076224613;
    p = p*w + 0.00943887047; p = p*w + 1.00167406;    p = p*w + 2.83297682;
  }
  double y = p * x;
  const double c = 1.1283791670955126;   // 2/sqrt(pi)
  #pragma unroll
  for (int it = 0; it < 3; it++){
    double err = erf(y) - x;
    y -= err / (c * exp(-y*y));
  }
  return y;
}

__device__ float bits_to_normal(unsigned b){
  float f = __uint_as_float((b >> 9) | 0x3f800000u) - 1.0f;
  const float lo = -0.99999994f;               // nextafter(-1,0) in f32
  float x = fmaxf(lo, f * 2.0f + lo);
  double r = 1.4142135623730951 * erfinv64((double)x);
  return (float)r;
}

__global__ __launch_bounds__(256) void k_omega(float* __restrict__ om){
  int i = blockIdx.x*256 + threadIdx.x;
  if (i >= 262144) return;
  unsigned o0, o1;
  tf2x32(0u, 42u, 0u, (unsigned)i, &o0, &o1);   // counter = (0, i)
  om[i] = bits_to_normal(o0 ^ o1);              // partitionable: bits1 ^ bits2
}

// ---------------- GEMM (fp32, tiled 64x64, 4x4/thread) ----------------
__global__ __launch_bounds__(256) void k_gemm_nn(int M, int Nn, int K,
      const float* __restrict__ A, int lda, const float* __restrict__ B, int ldb,
      float* __restrict__ Cc, int ldc, const float* __restrict__ rowscale,
      const float* __restrict__ kscale, const float* __restrict__ bias){
  __shared__ float As[16][65];
  __shared__ float Bs[16][65];
  int bm = blockIdx.y*64, bn = blockIdx.x*64;
  int t = threadIdx.x;
  int tr = t >> 4, tc = t & 15;
  float acc[4][4] = {};
  for (int k0 = 0; k0 < K; k0 += 16){
    #pragma unroll
    for (int q = 0; q < 4; q++){
      int idx = t*4 + q;
      int m = idx >> 4, kk = idx & 15;
      As[kk][m] = A[(size_t)(bm+m)*lda + (k0+kk)];
    }
    #pragma unroll
    for (int q = 0; q < 4; q++){
      int idx = t + q*256;
      int kk = idx >> 6, n = idx & 63;
      float ks = kscale ? kscale[k0+kk] : 1.0f;
      Bs[kk][n] = B[(size_t)(k0+kk)*ldb + (bn+n)] * ks;
    }
    __syncthreads();
    #pragma unroll
    for (int kk = 0; kk < 16; kk++){
      float a0 = As[kk][tr*4+0], a1 = As[kk][tr*4+1], a2 = As[kk][tr*4+2], a3 = As[kk][tr*4+3];
      float b0 = Bs[kk][tc*4+0], b1 = Bs[kk][tc*4+1], b2 = Bs[kk][tc*4+2], b3 = Bs[kk][tc*4+3];
      acc[0][0] += a0*b0; acc[0][1] += a0*b1; acc[0][2] += a0*b2; acc[0][3] += a0*b3;
      acc[1][0] += a1*b0; acc[1][1] += a1*b1; acc[1][2] += a1*b2; acc[1][3] += a1*b3;
      acc[2][0] += a2*b0; acc[2][1] += a2*b1; acc[2][2] += a2*b2; acc[2][3] += a2*b3;
      acc[3][0] += a3*b0; acc[3][1] += a3*b1; acc[3][2] += a3*b2; acc[3][3] += a3*b3;
    }
    __syncthreads();
  }
  #pragma unroll
  for (int i2 = 0; i2 < 4; i2++){
    int m = bm + tr*4 + i2;
    float rs = rowscale ? rowscale[m] : 1.0f;
    #pragma unroll
    for (int j2 = 0; j2 < 4; j2++){
      int n = bn + tc*4 + j2;
      float v = acc[i2][j2] * rs;
      if (bias) v += bias[n];
      Cc[(size_t)m*ldc + n] = v;
    }
  }
}

// split-K NN: C += partial (C pre-zeroed); grid (Nn/64, M/64, K/kchunk)
__global__ __launch_bounds__(256) void k_gemm_nn_sk(int M, int Nn, int K, int kchunk,
      const float* __restrict__ A, int lda, const float* __restrict__ B, int ldb,
      float* __restrict__ Cc, int ldc){
  __shared__ float As[16][65];
  __shared__ float Bs[16][65];
  int bm = blockIdx.y*64, bn = blockIdx.x*64;
  int kb = blockIdx.z*kchunk, ke = kb + kchunk;
  int t = threadIdx.x;
  int tr = t >> 4, tc = t & 15;
  float acc[4][4] = {};
  for (int k0 = kb; k0 < ke; k0 += 16){
    #pragma unroll
    for (int q = 0; q < 4; q++){
      int idx = t*4 + q;
      int m = idx >> 4, kk = idx & 15;
      As[kk][m] = A[(size_t)(bm+m)*lda + (k0+kk)];
    }
    #pragma unroll
    for (int q = 0; q < 4; q++){
      int idx = t + q*256;
      int kk = idx >> 6, n = idx & 63;
      Bs[kk][n] = B[(size_t)(k0+kk)*ldb + (bn+n)];
    }
    __syncthreads();
    #pragma unroll
    for (int kk = 0; kk < 16; kk++){
      float a0 = As[kk][tr*4+0], a1 = As[kk][tr*4+1], a2 = As[kk][tr*4+2], a3 = As[kk][tr*4+3];
      float b0 = Bs[kk][tc*4+0], b1 = Bs[kk][tc*4+1], b2 = Bs[kk][tc*4+2], b3 = Bs[kk][tc*4+3];
      acc[0][0] += a0*b0; acc[0][1] += a0*b1; acc[0][2] += a0*b2; acc[0][3] += a0*b3;
      acc[1][0] += a1*b0; acc[1][1] += a1*b1; acc[1][2] += a1*b2; acc[1][3] += a1*b3;
      acc[2][0] += a2*b0; acc[2][1] += a2*b1; acc[2][2] += a2*b2; acc[2][3] += a2*b3;
      acc[3][0] += a3*b0; acc[3][1] += a3*b1; acc[3][2] += a3*b2; acc[3][3] += a3*b3;
    }
    __syncthreads();
  }
  #pragma unroll
  for (int i2 = 0; i2 < 4; i2++){
    int m = bm + tr*4 + i2;
    #pragma unroll
    for (int j2 = 0; j2 < 4; j2++){
      int n = bn + tc*4 + j2;
      atomicAdd(&Cc[(size_t)m*ldc + n], acc[i2][j2]);
    }
  }
}

// split-K TN: C += partial (C pre-zeroed); grid (Nn/16, M/16, K/kchunk)
__global__ __launch_bounds__(256) void k_gemm_tn_sk(int M, int Nn, int K, int kchunk,
      const float* __restrict__ A, int lda, const float* __restrict__ B, int ldb,
      float* __restrict__ Cc, int ldc, const float* __restrict__ kscale){
  __shared__ float As[32][17];
  __shared__ float Bs[32][17];
  int bm = blockIdx.y*16, bn = blockIdx.x*16;
  int kb = blockIdx.z*kchunk, ke = kb + kchunk;
  int t = threadIdx.x;
  int tm = t >> 4, tn = t & 15;
  float acc = 0.f;
  for (int k0 = kb; k0 < ke; k0 += 32){
    #pragma unroll
    for (int q = 0; q < 2; q++){
      int idx = t + q*256;
      int kk = idx >> 4, m = idx & 15;
      float sv = kscale ? kscale[k0+kk] : 1.0f;
      As[kk][m] = A[(size_t)(k0+kk)*lda + (bm+m)] * sv;
      Bs[kk][m] = B[(size_t)(k0+kk)*ldb + (bn+m)];
    }
    __syncthreads();
    #pragma unroll
    for (int kk = 0; kk < 32; kk++) acc += As[kk][tm] * Bs[kk][tn];
    __syncthreads();
  }
  atomicAdd(&Cc[(size_t)(bm+tm)*ldc + (bn+tn)], acc);
}

// ---------------- f64 randomized-subspace chain ----------------
__global__ __launch_bounds__(64) void k_spmm64(const int* __restrict__ ptr, const int* __restrict__ eid,
                       const int* __restrict__ oidx, const float* __restrict__ coef,
                       const double* __restrict__ X, double* __restrict__ Y){
  int seg = blockIdx.x;
  int t = threadIdx.x;
  double acc = 0.0;
  int p0 = ptr[seg], p1 = ptr[seg+1];
  for (int p = p0; p < p1; ++p){
    int e = eid[p];
    acc += (double)coef[e] * X[(size_t)oidx[e]*RK + t];
  }
  Y[(size_t)seg*RK + t] = acc;
}
// Gram: G += Xslice^T Xslice over 64-row slices (G zeroed before)
__global__ __launch_bounds__(256) void k_gram64(const double* __restrict__ X, double* __restrict__ G){
  __shared__ double Xs[64][65];
  int b = blockIdx.x;
  int t = threadIdx.x;
  #pragma unroll
  for (int q = 0; q < 16; q++){
    int idx = t + q*256;
    Xs[idx >> 6][idx & 63] = X[(size_t)(b*64 + (idx >> 6))*RK + (idx & 63)];
  }
  __syncthreads();
  int i = t >> 2;
  int j0 = (t & 3) * 16;
  double acc[16];
  #pragma unroll
  for (int jj = 0; jj < 16; jj++) acc[jj] = 0.0;
  for (int k = 0; k < 64; k++){
    double a = Xs[k][i];
    #pragma unroll
    for (int jj = 0; jj < 16; jj++) acc[jj] += a * Xs[k][j0+jj];
  }
  #pragma unroll
  for (int jj = 0; jj < 16; jj++) atomicAdd(&G[i*RK + j0 + jj], acc[jj]);
}
// Cholesky + upper-tri inverse, f64 (r15): REGISTER-RESIDENT factorization.
// Thread t owns column j=t&63, rows i=4q+(t>>6), q=0..15 in registers.
// Per step: publish column k to LDS, trailing update = independent reg FMAs.
// L dumped to LDS once; wave-per-column back-substitution (multiply-only).
__global__ __launch_bounds__(256) void k_cholinv64(const double* __restrict__ G, double* __restrict__ Rinv){
  __shared__ double colk[64];
  __shared__ double sdinv[64];
  __shared__ double gl[64][65];
  int t = threadIdx.x;
  int wv = t >> 6, lane = t & 63;
  int j = lane;                   // owned column
  double r[16];                   // rows i = 4q + wv
  #pragma unroll
  for (int q = 0; q < 16; q++)
    r[q] = G[(size_t)(((q << 2) + wv) << 6) + j];
  for (int k = 0; k < 64; k++){
    int kq = k >> 2, kw = k & 3;
    if (wv == kw && j == k){
      double d = sqrt(fmax(r[kq], 1e-300));
      r[kq] = d;
      sdinv[k] = 1.0 / d;
    }
    __syncthreads();
    if (j == k){
      double di = sdinv[k];
      #pragma unroll
      for (int q = 0; q < 16; q++){
        int i = (q << 2) + wv;
        if (i > k){ r[q] *= di; colk[i] = r[q]; }
      }
    }
    __syncthreads();
    if (j > k){
      double cj = colk[j];
      #pragma unroll
      for (int q = 0; q < 16; q++){
        int i = (q << 2) + wv;
        if (i >= j) r[q] -= colk[i] * cj;   // i >= j > k
      }
    }
    __syncthreads();
  }
  // dump L to LDS for back-substitution
  #pragma unroll
  for (int q = 0; q < 16; q++)
    gl[(q << 2) + wv][j] = r[q];
  __syncthreads();
  // R = L^T; column c of R^{-1}, one wave per column
  for (int c = wv; c < 64; c += 4){
    double x = 0.0;
    if (lane == c) x = sdinv[c];
    for (int i = c - 1; i >= 0; i--){
      double p = (lane > i && lane <= c) ? gl[lane][i] * x : 0.0;
      #pragma unroll
      for (int off = 32; off > 0; off >>= 1) p += __shfl_down(p, off);
      double s = __shfl(p, 0);
      if (lane == i) x = -s * sdinv[i];
    }
    Rinv[lane*64 + c] = (lane <= c) ? x : 0.0;
  }
}
// dst[NNx64] = src[NNx64] * Rinv(upper); 4 rows per 256-thread block
__global__ __launch_bounds__(256) void k_applyR64(const double* __restrict__ src,
      const double* __restrict__ Rinv, double* __restrict__ dst){
  __shared__ double Rs[64][65];
  int t = threadIdx.x;
  #pragma unroll
  for (int q = 0; q < 16; q++){
    int idx = t + q*256;
    Rs[idx >> 6][idx & 63] = Rinv[idx];
  }
  __syncthreads();
  int r = blockIdx.x*4 + (t >> 6);
  int j = t & 63;
  const double* rowp = src + (size_t)r*RK;
  double s = 0.0;
  for (int k = 0; k <= j; k++) s += rowp[k] * Rs[k][j];
  dst[(size_t)r*RK + j] = s;
}
__global__ __launch_bounds__(256) void k_qsum64(const double* __restrict__ Q, double* __restrict__ qs){
  int j = blockIdx.x;  int t = threadIdx.x;
  double a = 0.0;
  for (int n = t; n < NN; n += 256) a += Q[(size_t)n*RK + j];
  __shared__ double sh[256];
  sh[t] = a; __syncthreads();
  for (int off = 128; off > 0; off >>= 1){ if (t < off) sh[t] += sh[t+off]; __syncthreads(); }
  if (t == 0) qs[j] = sh[0];
}
__global__ __launch_bounds__(256) void k_deg2f(const double* __restrict__ C, const double* __restrict__ qs,
                                               float* __restrict__ dinv2){
  int i = blockIdx.x*256 + threadIdx.x;
  if (i >= NN) return;
  double s = 0.0;
  #pragma unroll
  for (int k = 0; k < RK; k++) s += C[(size_t)i*RK + k] * qs[k];
  dinv2[i] = (s > 0.0) ? (float)(1.0/sqrt(s)) : 0.f;
}

// ---------------- SpMM over sorted edge lists (f32, branch 1) ----------------
__global__ void k_spmm(const int* __restrict__ ptr, const int* __restrict__ eid,
                       const int* __restrict__ oidx, const float* __restrict__ coef,
                       const float* __restrict__ X, int ldx,
                       float* __restrict__ Y, int ldy, int F,
                       const float* __restrict__ self_dinv, const float* __restrict__ bias){
  int seg = blockIdx.x;
  int t = threadIdx.x, bd = blockDim.x;
  int f1 = t + bd;
  bool two = (f1 < F);
  float acc0 = 0.f, acc1 = 0.f;
  if (self_dinv){
    float sd = self_dinv[seg]; float s2 = sd*sd;
    acc0 = s2 * X[(size_t)seg*ldx + t];
    if (two) acc1 = s2 * X[(size_t)seg*ldx + f1];
  }
  int p0 = ptr[seg], p1 = ptr[seg+1];
  for (int p = p0; p < p1; ++p){
    int e = eid[p];
    int o = oidx[e];
    float c = coef[e];
    const float* xr = X + (size_t)o*ldx;
    acc0 += c * xr[t];
    if (two) acc1 += c * xr[f1];
  }
  if (bias){ acc0 += bias[t]; if (two) acc1 += bias[f1]; }
  Y[(size_t)seg*ldy + t] = acc0;
  if (two) Y[(size_t)seg*ldy + f1] = acc1;
}

// ---------------- domain-specific BN ----------------
__global__ __launch_bounds__(256) void k_bnstats(const float* __restrict__ H, const int* __restrict__ y,
        const int* __restrict__ dcnt, const float* __restrict__ gamma, const float* __restrict__ beta,
        float* __restrict__ scal, float* __restrict__ shft){
  int j = blockIdx.x;
  int t = threadIdx.x;
  float s0=0,s1=0,s2=0,s3=0,q0=0,q1=0,q2=0,q3=0;
  for (int n = t; n < NN; n += 256){
    float v = H[(size_t)n*HIDC + j];
    int d = y[n];
    float v2 = v*v;
    if      (d == 0){ s0 += v; q0 += v2; }
    else if (d == 1){ s1 += v; q1 += v2; }
    else if (d == 2){ s2 += v; q2 += v2; }
    else            { s3 += v; q3 += v2; }
  }
  __shared__ float sh[256][8];
  sh[t][0]=s0; sh[t][1]=s1; sh[t][2]=s2; sh[t][3]=s3;
  sh[t][4]=q0; sh[t][5]=q1; sh[t][6]=q2; sh[t][7]=q3;
  __syncthreads();
  for (int off = 128; off > 0; off >>= 1){
    if (t < off){
      #pragma unroll
      for (int q = 0; q < 8; q++) sh[t][q] += sh[t+off][q];
    }
    __syncthreads();
  }
  if (t < NDOM){
    float cnt  = fmaxf((float)dcnt[t], 1.0f);
    float mean = sh[0][t] / cnt;
    float var  = fmaxf(sh[0][4+t] / cnt - mean*mean, 0.f);
    float inv  = 1.0f / sqrtf(var + EPSBN);
    float gmm  = gamma[t*HIDC + j];
    scal[t*HIDC + j] = gmm * inv;
    shft[t*HIDC + j] = beta[t*HIDC + j] - mean * gmm * inv;
  }
}
__global__ __launch_bounds__(256) void k_bnapply(float* __restrict__ H, const int* __restrict__ y,
        const float* __restrict__ scal, const float* __restrict__ shft){
  int idx = blockIdx.x*256 + threadIdx.x;
  if (idx >= NN*HIDC) return;
  int n = idx >> 9, j = idx & (HIDC-1);
  int d = y[n];
  float v = H[idx] * scal[d*HIDC + j] + shft[d*HIDC + j];
  H[idx] = v > 0.f ? v : 0.f;
}

// ---------------- launch ----------------
extern "C" void kernel_launch(void* const* d_in, const int* in_sizes, int n_in,
                              void* d_out, int out_size, void* d_ws, size_t ws_size,
                              hipStream_t stream){
  (void)in_sizes; (void)n_in; (void)out_size;
  const void* x_in  = d_in[0];
  const int*  ei    = (const int*)d_in[1];
  const void* w_in  = d_in[2];
  const int*  yv    = (const int*)d_in[3];
  const void* W1i   = d_in[4];
  const void* b1i   = d_in[5];
  const void* Wmui  = d_in[6];
  const void* bmui  = d_in[7];
  const void* Wlvi  = d_in[8];
  const void* blvi  = d_in[9];
  const void* gmi   = d_in[10];
  const void* bti   = d_in[11];
  const int* rowA = ei;
  const int* colA = ei + NEDG;

  // ---- workspace: doubles | floats | ints (~38 MB) ----
  double* Dp = (double*)d_ws;
  size_t od = 0;
  double* Qd0 = Dp + od; od += (size_t)NN*RK;
  double* Qd1 = Dp + od; od += (size_t)NN*RK;
  double* Cd  = Dp + od; od += (size_t)NN*RK;
  double* Gd  = Dp + od; od += RK*RK;
  double* Rid = Dp + od; od += RK*RK;
  double* qsd = Dp + od; od += RK;
  float* Fp = (float*)(Dp + od);
  size_t o = 0;
  float* xf   = Fp + o; o += (size_t)NN*INC;       // reused as h1/h2 buffer
  float* W1f  = Fp + o; o += (size_t)INC*HIDC;
  float* b1f  = Fp + o; o += HIDC;
  float* Wmuf = Fp + o; o += (size_t)HIDC*OUTC;
  float* bmuf = Fp + o; o += OUTC;
  float* Wlvf = Fp + o; o += (size_t)HIDC*OUTC;
  float* blvf = Fp + o; o += OUTC;
  float* gmf  = Fp + o; o += NDOM*HIDC;
  float* btf  = Fp + o; o += NDOM*HIDC;
  float* wf   = Fp + o; o += NEDG;
  float* xw1  = Fp + o; o += (size_t)NN*HIDC;
  float* hwA  = Fp + o; o += (size_t)NN*OUTC;
  float* hwB  = Fp + o; o += (size_t)NN*OUTC;     // contiguous after hwA
  float* Bf0  = Fp + o; o += (size_t)NN*RK;        // omega (f32)
  float* Bf1  = Fp + o; o += (size_t)NN*RK;        // Qb (f32)
  float* Cm   = Fp + o; o += (size_t)NN*RK;        // C (f32)
  float* Tm   = Fp + o; o += (size_t)RK*HIDC;
  float* Umu  = Fp + o; o += RK*RK;
  float* deg1 = Fp + o; o += NN;
  float* dinv1= Fp + o; o += NN;
  float* dinv2= Fp + o; o += NN;
  float* norm1= Fp + o; o += NEDG;
  float* scal = Fp + o; o += NDOM*HIDC;
  float* shft = Fp + o; o += NDOM*HIDC;
  float* zb   = Fp + o; o += (size_t)4*NN*OUTC;
  int* Ip = (int*)(Fp + o);
  size_t oi = 0;
  int* cntR = Ip + oi; oi += NN;
  int* ptrR = Ip + oi; oi += NN + 1;
  int* posR = Ip + oi; oi += NN;
  int* eidR = Ip + oi; oi += NEDG;
  int* cntC = Ip + oi; oi += NN;
  int* ptrC = Ip + oi; oi += NN + 1;
  int* posC = Ip + oi; oi += NN;
  int* eidC = Ip + oi; oi += NEDG;
  int* dcnt = Ip + oi; oi += NDOM;
  int* dflag= Ip + oi; oi += 1;

  size_t need = od*sizeof(double) + o*sizeof(float) + (oi+16)*sizeof(int);
  if (ws_size < need) return;

  float* hbuf = xf;  // x dead after xw1 GEMM

  const int T = 256;
  k_detect<<<1,T,0,stream>>>((const unsigned short*)x_in, dflag);
  k_upcast<<<cdiv(NN*INC,T),T,0,stream>>>(x_in, dflag, xf, NN*INC);
  k_upcast<<<cdiv(INC*HIDC,T),T,0,stream>>>(W1i, dflag, W1f, INC*HIDC);
  k_upcast<<<cdiv(HIDC,T),T,0,stream>>>(b1i, dflag, b1f, HIDC);
  k_upcast<<<cdiv(HIDC*OUTC,T),T,0,stream>>>(Wmui, dflag, Wmuf, HIDC*OUTC);
  k_upcast<<<1,T,0,stream>>>(bmui, dflag, bmuf, OUTC);
  k_upcast<<<cdiv(HIDC*OUTC,T),T,0,stream>>>(Wlvi, dflag, Wlvf, HIDC*OUTC);
  k_upcast<<<1,T,0,stream>>>(blvi, dflag, blvf, OUTC);
  k_upcast<<<cdiv(NDOM*HIDC,T),T,0,stream>>>(gmi, dflag, gmf, NDOM*HIDC);
  k_upcast<<<cdiv(NDOM*HIDC,T),T,0,stream>>>(bti, dflag, btf, NDOM*HIDC);
  k_upcast<<<cdiv(NEDG,T),T,0,stream>>>(w_in, dflag, wf, NEDG);

  k_fill <<<cdiv(NN,T),T,0,stream>>>(deg1, 1.0f, NN);   // self-loop weight 1
  k_filli<<<cdiv(NN,T),T,0,stream>>>(cntR, 0, NN);
  k_filli<<<cdiv(NN,T),T,0,stream>>>(cntC, 0, NN);
  k_filli<<<1,T,0,stream>>>(dcnt, 0, NDOM);
  k_hist <<<cdiv(NEDG,T),T,0,stream>>>(rowA, colA, wf, deg1, cntR, cntC);
  k_dinv <<<cdiv(NN,T),T,0,stream>>>(deg1, dinv1, NN);
  k_norm1<<<cdiv(NEDG,T),T,0,stream>>>(rowA, colA, wf, dinv1, norm1);
  k_scan4096<<<1,1024,0,stream>>>(cntR, ptrR, posR);
  k_scan4096<<<1,1024,0,stream>>>(cntC, ptrC, posC);
  k_scatter<<<cdiv(NEDG,T),T,0,stream>>>(rowA, colA, posR, posC, eidR, eidC);
  k_omega<<<cdiv(262144,T),T,0,stream>>>(Bf0);
  k_dcnt <<<cdiv(NN,T),T,0,stream>>>(yv, dcnt);

  // ---- branch 1 (verified) ----
  k_gemm_nn<<<dim3(HIDC/64, NN/64),256,0,stream>>>(NN,HIDC,INC, xf,INC, W1f,HIDC, xw1,HIDC, nullptr,nullptr,nullptr);
  k_spmm<<<NN,256,0,stream>>>(ptrC,eidC,rowA,norm1, xw1,HIDC, hbuf,HIDC, HIDC, dinv1, b1f);
  k_bnstats<<<HIDC,256,0,stream>>>(hbuf, yv, dcnt, gmf, btf, scal, shft);
  k_bnapply<<<cdiv(NN*HIDC,T),T,0,stream>>>(hbuf, yv, scal, shft);
  k_fill<<<cdiv(2*NN*OUTC,T),T,0,stream>>>(hwA, 0.f, 2*NN*OUTC);   // hwA|hwB contiguous
  k_gemm_nn_sk<<<dim3(1, NN/64, 4),256,0,stream>>>(NN,OUTC,HIDC,128, hbuf,HIDC, Wmuf,OUTC, hwA,OUTC);
  k_gemm_nn_sk<<<dim3(1, NN/64, 4),256,0,stream>>>(NN,OUTC,HIDC,128, hbuf,HIDC, Wlvf,OUTC, hwB,OUTC);
  k_spmm<<<NN,64,0,stream>>>(ptrC,eidC,rowA,norm1, hwA,OUTC, zb + 0*NN*OUTC,OUTC, OUTC, dinv1, bmuf);
  k_spmm<<<NN,64,0,stream>>>(ptrC,eidC,rowA,norm1, hwB,OUTC, zb + 1*NN*OUTC,OUTC, OUTC, dinv1, blvf);

  // ---- branch 2: f64 subspace (mid QR1 + final QR1), factored A2 ----
  auto spmmA64 = [&](const double* s, double* d){   // d = A @ s
    k_spmm64<<<NN,64,0,stream>>>(ptrR,eidR,colA,wf, s, d);
  };
  auto spmmAT64 = [&](const double* s, double* d){  // d = A^T @ s
    k_spmm64<<<NN,64,0,stream>>>(ptrC,eidC,rowA,wf, s, d);
  };
  auto orth164 = [&](double* src, double* dst){     // dst = src * R^{-1}
    k_filld<<<cdiv(RK*RK,T),T,0,stream>>>(Gd, 0.0, RK*RK);
    k_gram64<<<NN/64,256,0,stream>>>(src, Gd);
    k_cholinv64<<<1,256,0,stream>>>(Gd, Rid);
    k_applyR64<<<NN/4,256,0,stream>>>(src, Rid, dst);
  };

  k_f32to64<<<cdiv(NN*RK,T),T,0,stream>>>(Bf0, Qd0, NN*RK);
  spmmA64 (Qd0, Qd1);                      // P1 -> Qd1
  spmmAT64(Qd1, Qd0);                      // P2 -> Qd0
  spmmA64 (Qd0, Qd1);                      // P3 -> Qd1
  orth164(Qd1, Qd0);                       // mid QR1 -> Qd0 (range-exact)
  spmmAT64(Qd0, Qd1);                      // P4 -> Qd1
  spmmA64 (Qd1, Qd0);                      // P5 -> Qd0 (kappa ~ 25)
  orth164(Qd0, Qd1);                       // final QR1 -> Qb in Qd1 (orth ~6e-14)
  spmmAT64(Qd1, Cd);                       // C = A^T Qb  (A2 = Qb C^T)
  k_qsum64<<<RK,256,0,stream>>>(Qd1, qsd);
  k_deg2f<<<cdiv(NN,T),T,0,stream>>>(Cd, qsd, dinv2);
  k_f64to32<<<cdiv(NN*RK,T),T,0,stream>>>(Qd1, Bf1, NN*RK);
  k_f64to32<<<cdiv(NN*RK,T),T,0,stream>>>(Cd,  Cm,  NN*RK);

  // h2 = dsbn_relu( D C (Qb^T (D xw1)) + b1 )
  k_fill<<<cdiv(RK*HIDC,T),T,0,stream>>>(Tm, 0.f, RK*HIDC);
  k_gemm_tn_sk<<<dim3(HIDC/16, RK/16, 8),256,0,stream>>>(RK,HIDC,NN,512, Bf1,RK, xw1,HIDC, Tm,HIDC, dinv2);
  k_gemm_nn<<<dim3(HIDC/64, NN/64),256,0,stream>>>(NN,HIDC,RK, Cm,RK, Tm,HIDC, hbuf,HIDC, dinv2, nullptr, b1f);
  k_bnstats<<<HIDC,256,0,stream>>>(hbuf, yv, dcnt, gmf, btf, scal, shft);
  k_bnapply<<<cdiv(NN*HIDC,T),T,0,stream>>>(hbuf, yv, scal, shft);
  // z2 = D C (Qb^T (D (h2 W))) + b
  k_fill<<<cdiv(2*NN*OUTC,T),T,0,stream>>>(hwA, 0.f, 2*NN*OUTC);
  k_gemm_nn_sk<<<dim3(1, NN/64, 4),256,0,stream>>>(NN,OUTC,HIDC,128, hbuf,HIDC, Wmuf,OUTC, hwA,OUTC);
  k_gemm_nn_sk<<<dim3(1, NN/64, 4),256,0,stream>>>(NN,OUTC,HIDC,128, hbuf,HIDC, Wlvf,OUTC, hwB,OUTC);
  k_fill<<<cdiv(RK*RK,T),T,0,stream>>>(Umu, 0.f, RK*RK);
  k_gemm_tn_sk<<<dim3(RK/16, RK/16, 16),256,0,stream>>>(RK,RK,NN,256, Bf1,RK, hwA,OUTC, Umu,RK, dinv2);
  k_gemm_nn<<<dim3(1, NN/64),256,0,stream>>>(NN,OUTC,RK, Cm,RK, Umu,RK, zb + 2*NN*OUTC,OUTC, dinv2, nullptr, bmuf);
  k_fill<<<cdiv(RK*RK,T),T,0,stream>>>(Umu, 0.f, RK*RK);
  k_gemm_tn_sk<<<dim3(RK/16, RK/16, 16),256,0,stream>>>(RK,RK,NN,256, Bf1,RK, hwB,OUTC, Umu,RK, dinv2);
  k_gemm_nn<<<dim3(1, NN/64),256,0,stream>>>(NN,OUTC,RK, Cm,RK, Umu,RK, zb + 3*NN*OUTC,OUTC, dinv2, nullptr, blvf);

  // outputs -> f32
  k_copy<<<cdiv(4*NN*OUTC,T),T,0,stream>>>(zb, (float*)d_out, 4*NN*OUTC);
}

// Round 16
// 1139.027 us; speedup vs baseline: 1.2232x; 1.2232x over previous
//
#include <hip/hip_runtime.h>
#include <hip/hip_bf16.h>

// GCNEncoder — PASSING (absmax .0039; r15 dur 1393us). Correct omega:
// partitionable threefry (counter (0,i), bits = o0^o1), f64 erfinv.
// r16 perf: cholinv stuck at ~248us with VALUBusy 0.028% -> pure latency in
// the wave-shuffle back-substitution (f64 __shfl = 2x cross-lane LDS ops,
// ~120cy each, ~7 deep per iteration, ~480 dependent iterations). Replace
// with per-thread column solve: thread c solves R x = e_c serially, x in its
// own LDS column — no shuffles, no barriers; 4-way unrolled partial sums.
// Cholesky factorization stays register-resident (r15).

#define NN    4096
#define NEDG  131072
#define INC   512
#define HIDC  512
#define OUTC  64
#define RK    64
#define NDOM  4
#define EPSBN 1e-5f

static inline int cdiv(int a, int b){ return (a + b - 1) / b; }

// ---------------- input dtype detection (f32 vs bf16 carriers) ----------------
__global__ __launch_bounds__(256) void k_detect(const unsigned short* __restrict__ p,
                                                int* __restrict__ flag){
  int t = threadIdx.x;
  int cnt = 0;
  for (int i = t; i < 4096; i += 256){
    unsigned short v = p[2*i];
    int e = (v >> 7) & 0xFF;
    if (e >= 100 && e <= 140) cnt++;
  }
  __shared__ int sh[256];
  sh[t] = cnt; __syncthreads();
  for (int off = 128; off > 0; off >>= 1){ if (t < off) sh[t] += sh[t+off]; __syncthreads(); }
  if (t == 0) *flag = (sh[0] >= 2048) ? 0 : 1;
}

// ---------------- elementwise utils ----------------
__global__ __launch_bounds__(256) void k_upcast(const void* __restrict__ s,
                                                const int* __restrict__ isf32,
                                                float* __restrict__ d, int n){
  int i = blockIdx.x*256 + threadIdx.x;
  if (i >= n) return;
  if (*isf32) d[i] = ((const float*)s)[i];
  else        d[i] = __bfloat162float(((const __hip_bfloat16*)s)[i]);
}
__global__ __launch_bounds__(256) void k_fill(float* d, float v, int n){
  int i = blockIdx.x*256 + threadIdx.x;
  if (i < n) d[i] = v;
}
__global__ __launch_bounds__(256) void k_filli(int* d, int v, int n){
  int i = blockIdx.x*256 + threadIdx.x;
  if (i < n) d[i] = v;
}
__global__ __launch_bounds__(256) void k_filld(double* d, double v, int n){
  int i = blockIdx.x*256 + threadIdx.x;
  if (i < n) d[i] = v;
}
__global__ __launch_bounds__(256) void k_copy(const float* __restrict__ z,
                                              float* __restrict__ o, int n){
  int i = blockIdx.x*256 + threadIdx.x;
  if (i < n) o[i] = z[i];
}
__global__ __launch_bounds__(256) void k_f32to64(const float* __restrict__ s,
                                                 double* __restrict__ d, int n){
  int i = blockIdx.x*256 + threadIdx.x;
  if (i < n) d[i] = (double)s[i];
}
__global__ __launch_bounds__(256) void k_f64to32(const double* __restrict__ s,
                                                 float* __restrict__ d, int n){
  int i = blockIdx.x*256 + threadIdx.x;
  if (i < n) d[i] = (float)s[i];
}

// ---------------- graph preprocessing ----------------
__global__ __launch_bounds__(256) void k_hist(const int* __restrict__ row, const int* __restrict__ col,
                                              const float* __restrict__ w, float* deg,
                                              int* cntR, int* cntC){
  int e = blockIdx.x*256 + threadIdx.x;
  if (e < NEDG){
    atomicAdd(&deg[col[e]], w[e]);
    atomicAdd(&cntR[row[e]], 1);
    atomicAdd(&cntC[col[e]], 1);
  }
}
__global__ __launch_bounds__(256) void k_dinv(const float* deg, float* dinv, int n){
  int i = blockIdx.x*256 + threadIdx.x;
  if (i < n){ float d = deg[i]; dinv[i] = (d > 0.f) ? 1.f/sqrtf(d) : 0.f; }
}
__global__ __launch_bounds__(256) void k_norm1(const int* __restrict__ row, const int* __restrict__ col,
                                               const float* __restrict__ w, const float* __restrict__ dinv,
                                               float* __restrict__ nrm){
  int e = blockIdx.x*256 + threadIdx.x;
  if (e < NEDG) nrm[e] = dinv[row[e]] * w[e] * dinv[col[e]];
}
__global__ __launch_bounds__(1024) void k_scan4096(const int* __restrict__ cnt,
                                                   int* __restrict__ ptr, int* __restrict__ pos){
  __shared__ int sh[1024];
  int t = threadIdx.x;
  int b = t*4;
  int a0 = cnt[b], a1 = cnt[b+1], a2 = cnt[b+2], a3 = cnt[b+3];
  sh[t] = a0 + a1 + a2 + a3;
  __syncthreads();
  for (int off = 1; off < 1024; off <<= 1){
    int v = (t >= off) ? sh[t-off] : 0;
    __syncthreads();
    sh[t] += v;
    __syncthreads();
  }
  int excl = (t == 0) ? 0 : sh[t-1];
  ptr[b]   = excl;            pos[b]   = excl;
  ptr[b+1] = excl+a0;         pos[b+1] = excl+a0;
  ptr[b+2] = excl+a0+a1;      pos[b+2] = excl+a0+a1;
  ptr[b+3] = excl+a0+a1+a2;   pos[b+3] = excl+a0+a1+a2;
  if (t == 1023) ptr[4096] = sh[1023];
}
__global__ __launch_bounds__(256) void k_scatter(const int* __restrict__ row, const int* __restrict__ col,
                                                 int* posR, int* posC, int* eidR, int* eidC){
  int e = blockIdx.x*256 + threadIdx.x;
  if (e < NEDG){
    int p = atomicAdd(&posR[row[e]], 1); eidR[p] = e;
    int q = atomicAdd(&posC[col[e]], 1); eidC[q] = e;
  }
}
__global__ __launch_bounds__(256) void k_dcnt(const int* __restrict__ y, int* dcnt){
  int i = blockIdx.x*256 + threadIdx.x;
  if (i < NN) atomicAdd(&dcnt[y[i]], 1);
}

// ---------------- threefry2x32 core (KAT-verified round 8) ----------------
__device__ __forceinline__ unsigned rotl32(unsigned x, unsigned d){ return (x << d) | (x >> (32u - d)); }
#define TF_ROUND4(R0,R1,R2,R3) \
  x0 += x1; x1 = rotl32(x1,R0); x1 ^= x0; \
  x0 += x1; x1 = rotl32(x1,R1); x1 ^= x0; \
  x0 += x1; x1 = rotl32(x1,R2); x1 ^= x0; \
  x0 += x1; x1 = rotl32(x1,R3); x1 ^= x0;

__device__ __forceinline__ void tf2x32(unsigned k0, unsigned k1, unsigned c0, unsigned c1,
                                       unsigned* o0, unsigned* o1){
  unsigned ks2 = 0x1BD11BDAu ^ k0 ^ k1;
  unsigned x0 = c0 + k0, x1 = c1 + k1;
  TF_ROUND4(13,15,26,6);   x0 += k1;  x1 += ks2 + 1u;
  TF_ROUND4(17,29,16,24);  x0 += ks2; x1 += k0 + 2u;
  TF_ROUND4(13,15,26,6);   x0 += k0;  x1 += k1 + 3u;
  TF_ROUND4(17,29,16,24);  x0 += k1;  x1 += ks2 + 4u;
  TF_ROUND4(13,15,26,6);   x0 += ks2; x1 += k0 + 5u;
  *o0 = x0; *o1 = x1;
}

// ---------------- omega (verified round 10) ----------------
__device__ double erfinv64(double x){
  double w = -log1p(-x*x);
  double p;
  if (w < 5.0){
    w -= 2.5;
    p = 2.81022636e-08;  p = p*w + 3.43273939e-07; p = p*w - 3.5233877e-06;
    p = p*w - 4.39150654e-06; p = p*w + 0.00021858087; p = p*w - 0.00125372503;
    p = p*w - 0.00417768164;  p = p*w + 0.246640727;   p = p*w + 1.50140941;
  } else {
    w = sqrt(w) - 3.0;
    p = -0.000200214257; p = p*w + 0.000100950558; p = p*w + 0.00134934322;
    p = p*w - 0.00367342844; p = p*w + 0.00573950773; p = p*w - 0.0076224613;
    p = p*w + 0.00943887047; p = p*w + 1.00167406;    p = p*w + 2.83297682;
  }
  double y = p * x;
  const double c = 1.1283791670955126;   // 2/sqrt(pi)
  #pragma unroll
  for (int it = 0; it < 3; it++){
    double err = erf(y) - x;
    y -= err / (c * exp(-y*y));
  }
  return y;
}

__device__ float bits_to_normal(unsigned b){
  float f = __uint_as_float((b >> 9) | 0x3f800000u) - 1.0f;
  const float lo = -0.99999994f;               // nextafter(-1,0) in f32
  float x = fmaxf(lo, f * 2.0f + lo);
  double r = 1.4142135623730951 * erfinv64((double)x);
  return (float)r;
}

__global__ __launch_bounds__(256) void k_omega(float* __restrict__ om){
  int i = blockIdx.x*256 + threadIdx.x;
  if (i >= 262144) return;
  unsigned o0, o1;
  tf2x32(0u, 42u, 0u, (unsigned)i, &o0, &o1);   // counter = (0, i)
  om[i] = bits_to_normal(o0 ^ o1);              // partitionable: bits1 ^ bits2
}

// ---------------- GEMM (fp32, tiled 64x64, 4x4/thread) ----------------
__global__ __launch_bounds__(256) void k_gemm_nn(int M, int Nn, int K,
      const float* __restrict__ A, int lda, const float* __restrict__ B, int ldb,
      float* __restrict__ Cc, int ldc, const float* __restrict__ rowscale,
      const float* __restrict__ kscale, const float* __restrict__ bias){
  __shared__ float As[16][65];
  __shared__ float Bs[16][65];
  int bm = blockIdx.y*64, bn = blockIdx.x*64;
  int t = threadIdx.x;
  int tr = t >> 4, tc = t & 15;
  float acc[4][4] = {};
  for (int k0 = 0; k0 < K; k0 += 16){
    #pragma unroll
    for (int q = 0; q < 4; q++){
      int idx = t*4 + q;
      int m = idx >> 4, kk = idx & 15;
      As[kk][m] = A[(size_t)(bm+m)*lda + (k0+kk)];
    }
    #pragma unroll
    for (int q = 0; q < 4; q++){
      int idx = t + q*256;
      int kk = idx >> 6, n = idx & 63;
      float ks = kscale ? kscale[k0+kk] : 1.0f;
      Bs[kk][n] = B[(size_t)(k0+kk)*ldb + (bn+n)] * ks;
    }
    __syncthreads();
    #pragma unroll
    for (int kk = 0; kk < 16; kk++){
      float a0 = As[kk][tr*4+0], a1 = As[kk][tr*4+1], a2 = As[kk][tr*4+2], a3 = As[kk][tr*4+3];
      float b0 = Bs[kk][tc*4+0], b1 = Bs[kk][tc*4+1], b2 = Bs[kk][tc*4+2], b3 = Bs[kk][tc*4+3];
      acc[0][0] += a0*b0; acc[0][1] += a0*b1; acc[0][2] += a0*b2; acc[0][3] += a0*b3;
      acc[1][0] += a1*b0; acc[1][1] += a1*b1; acc[1][2] += a1*b2; acc[1][3] += a1*b3;
      acc[2][0] += a2*b0; acc[2][1] += a2*b1; acc[2][2] += a2*b2; acc[2][3] += a2*b3;
      acc[3][0] += a3*b0; acc[3][1] += a3*b1; acc[3][2] += a3*b2; acc[3][3] += a3*b3;
    }
    __syncthreads();
  }
  #pragma unroll
  for (int i2 = 0; i2 < 4; i2++){
    int m = bm + tr*4 + i2;
    float rs = rowscale ? rowscale[m] : 1.0f;
    #pragma unroll
    for (int j2 = 0; j2 < 4; j2++){
      int n = bn + tc*4 + j2;
      float v = acc[i2][j2] * rs;
      if (bias) v += bias[n];
      Cc[(size_t)m*ldc + n] = v;
    }
  }
}

// split-K NN: C += partial (C pre-zeroed); grid (Nn/64, M/64, K/kchunk)
__global__ __launch_bounds__(256) void k_gemm_nn_sk(int M, int Nn, int K, int kchunk,
      const float* __restrict__ A, int lda, const float* __restrict__ B, int ldb,
      float* __restrict__ Cc, int ldc){
  __shared__ float As[16][65];
  __shared__ float Bs[16][65];
  int bm = blockIdx.y*64, bn = blockIdx.x*64;
  int kb = blockIdx.z*kchunk, ke = kb + kchunk;
  int t = threadIdx.x;
  int tr = t >> 4, tc = t & 15;
  float acc[4][4] = {};
  for (int k0 = kb; k0 < ke; k0 += 16){
    #pragma unroll
    for (int q = 0; q < 4; q++){
      int idx = t*4 + q;
      int m = idx >> 4, kk = idx & 15;
      As[kk][m] = A[(size_t)(bm+m)*lda + (k0+kk)];
    }
    #pragma unroll
    for (int q = 0; q < 4; q++){
      int idx = t + q*256;
      int kk = idx >> 6, n = idx & 63;
      Bs[kk][n] = B[(size_t)(k0+kk)*ldb + (bn+n)];
    }
    __syncthreads();
    #pragma unroll
    for (int kk = 0; kk < 16; kk++){
      float a0 = As[kk][tr*4+0], a1 = As[kk][tr*4+1], a2 = As[kk][tr*4+2], a3 = As[kk][tr*4+3];
      float b0 = Bs[kk][tc*4+0], b1 = Bs[kk][tc*4+1], b2 = Bs[kk][tc*4+2], b3 = Bs[kk][tc*4+3];
      acc[0][0] += a0*b0; acc[0][1] += a0*b1; acc[0][2] += a0*b2; acc[0][3] += a0*b3;
      acc[1][0] += a1*b0; acc[1][1] += a1*b1; acc[1][2] += a1*b2; acc[1][3] += a1*b3;
      acc[2][0] += a2*b0; acc[2][1] += a2*b1; acc[2][2] += a2*b2; acc[2][3] += a2*b3;
      acc[3][0] += a3*b0; acc[3][1] += a3*b1; acc[3][2] += a3*b2; acc[3][3] += a3*b3;
    }
    __syncthreads();
  }
  #pragma unroll
  for (int i2 = 0; i2 < 4; i2++){
    int m = bm + tr*4 + i2;
    #pragma unroll
    for (int j2 = 0; j2 < 4; j2++){
      int n = bn + tc*4 + j2;
      atomicAdd(&Cc[(size_t)m*ldc + n], acc[i2][j2]);
    }
  }
}

// split-K TN: C += partial (C pre-zeroed); grid (Nn/16, M/16, K/kchunk)
__global__ __launch_bounds__(256) void k_gemm_tn_sk(int M, int Nn, int K, int kchunk,
      const float* __restrict__ A, int lda, const float* __restrict__ B, int ldb,
      float* __restrict__ Cc, int ldc, const float* __restrict__ kscale){
  __shared__ float As[32][17];
  __shared__ float Bs[32][17];
  int bm = blockIdx.y*16, bn = blockIdx.x*16;
  int kb = blockIdx.z*kchunk, ke = kb + kchunk;
  int t = threadIdx.x;
  int tm = t >> 4, tn = t & 15;
  float acc = 0.f;
  for (int k0 = kb; k0 < ke; k0 += 32){
    #pragma unroll
    for (int q = 0; q < 2; q++){
      int idx = t + q*256;
      int kk = idx >> 4, m = idx & 15;
      float sv = kscale ? kscale[k0+kk] : 1.0f;
      As[kk][m] = A[(size_t)(k0+kk)*lda + (bm+m)] * sv;
      Bs[kk][m] = B[(size_t)(k0+kk)*ldb + (bn+m)];
    }
    __syncthreads();
    #pragma unroll
    for (int kk = 0; kk < 32; kk++) acc += As[kk][tm] * Bs[kk][tn];
    __syncthreads();
  }
  atomicAdd(&Cc[(size_t)(bm+tm)*ldc + (bn+tn)], acc);
}

// ---------------- f64 randomized-subspace chain ----------------
__global__ __launch_bounds__(64) void k_spmm64(const int* __restrict__ ptr, const int* __restrict__ eid,
                       const int* __restrict__ oidx, const float* __restrict__ coef,
                       const double* __restrict__ X, double* __restrict__ Y){
  int seg = blockIdx.x;
  int t = threadIdx.x;
  double acc = 0.0;
  int p0 = ptr[seg], p1 = ptr[seg+1];
  for (int p = p0; p < p1; ++p){
    int e = eid[p];
    acc += (double)coef[e] * X[(size_t)oidx[e]*RK + t];
  }
  Y[(size_t)seg*RK + t] = acc;
}
// Gram: G += Xslice^T Xslice over 64-row slices (G zeroed before)
__global__ __launch_bounds__(256) void k_gram64(const double* __restrict__ X, double* __restrict__ G){
  __shared__ double Xs[64][65];
  int b = blockIdx.x;
  int t = threadIdx.x;
  #pragma unroll
  for (int q = 0; q < 16; q++){
    int idx = t + q*256;
    Xs[idx >> 6][idx & 63] = X[(size_t)(b*64 + (idx >> 6))*RK + (idx & 63)];
  }
  __syncthreads();
  int i = t >> 2;
  int j0 = (t & 3) * 16;
  double acc[16];
  #pragma unroll
  for (int jj = 0; jj < 16; jj++) acc[jj] = 0.0;
  for (int k = 0; k < 64; k++){
    double a = Xs[k][i];
    #pragma unroll
    for (int jj = 0; jj < 16; jj++) acc[jj] += a * Xs[k][j0+jj];
  }
  #pragma unroll
  for (int jj = 0; jj < 16; jj++) atomicAdd(&G[i*RK + j0 + jj], acc[jj]);
}
// Cholesky + upper-tri inverse, f64 (r16): register-resident factorization
// (r15) + per-thread column back-substitution — NO shuffles, NO barriers in
// the solve; thread c keeps x in its own LDS column, 4-way unrolled sums.
__global__ __launch_bounds__(256) void k_cholinv64(const double* __restrict__ G, double* __restrict__ Rinv){
  __shared__ double colk[64];
  __shared__ double sdinv[64];
  __shared__ double gl[64][65];
  __shared__ double Xc[64][65];
  int t = threadIdx.x;
  int wv = t >> 6, lane = t & 63;
  int j = lane;                   // owned column
  double r[16];                   // rows i = 4q + wv
  #pragma unroll
  for (int q = 0; q < 16; q++)
    r[q] = G[(size_t)(((q << 2) + wv) << 6) + j];
  for (int k = 0; k < 64; k++){
    int kq = k >> 2, kw = k & 3;
    if (wv == kw && j == k){
      double d = sqrt(fmax(r[kq], 1e-300));
      r[kq] = d;
      sdinv[k] = 1.0 / d;
    }
    __syncthreads();
    if (j == k){
      double di = sdinv[k];
      #pragma unroll
      for (int q = 0; q < 16; q++){
        int i = (q << 2) + wv;
        if (i > k){ r[q] *= di; colk[i] = r[q]; }
      }
    }
    __syncthreads();
    if (j > k){
      double cj = colk[j];
      #pragma unroll
      for (int q = 0; q < 16; q++){
        int i = (q << 2) + wv;
        if (i >= j) r[q] -= colk[i] * cj;   // i >= j > k
      }
    }
    __syncthreads();
  }
  // dump L to LDS for back-substitution
  #pragma unroll
  for (int q = 0; q < 16; q++)
    gl[(q << 2) + wv][j] = r[q];
  __syncthreads();
  // back-sub: thread c (< 64) solves R x = e_c; R[i][k] = L[k][i] = gl[k][i].
  // x lives in Xc[.][c] (own column) — no cross-thread deps, no barriers.
  if (t < 64){
    int c = t;
    Xc[c][c] = sdinv[c];
    for (int i = c - 1; i >= 0; i--){
      double s0 = 0.0, s1 = 0.0, s2 = 0.0, s3 = 0.0;
      int k = i + 1;
      for (; k + 3 <= c; k += 4){
        s0 += gl[k  ][i] * Xc[k  ][c];
        s1 += gl[k+1][i] * Xc[k+1][c];
        s2 += gl[k+2][i] * Xc[k+2][c];
        s3 += gl[k+3][i] * Xc[k+3][c];
      }
      for (; k <= c; k++) s0 += gl[k][i] * Xc[k][c];
      Xc[i][c] = -((s0 + s1) + (s2 + s3)) * sdinv[i];
    }
    for (int i = 0; i < 64; i++)
      Rinv[i*64 + c] = (i <= c) ? Xc[i][c] : 0.0;
  }
}
// dst[NNx64] = src[NNx64] * Rinv(upper); 4 rows per 256-thread block
__global__ __launch_bounds__(256) void k_applyR64(const double* __restrict__ src,
      const double* __restrict__ Rinv, double* __restrict__ dst){
  __shared__ double Rs[64][65];
  int t = threadIdx.x;
  #pragma unroll
  for (int q = 0; q < 16; q++){
    int idx = t + q*256;
    Rs[idx >> 6][idx & 63] = Rinv[idx];
  }
  __syncthreads();
  int r = blockIdx.x*4 + (t >> 6);
  int j = t & 63;
  const double* rowp = src + (size_t)r*RK;
  double s = 0.0;
  for (int k = 0; k <= j; k++) s += rowp[k] * Rs[k][j];
  dst[(size_t)r*RK + j] = s;
}
__global__ __launch_bounds__(256) void k_qsum64(const double* __restrict__ Q, double* __restrict__ qs){
  int j = blockIdx.x;  int t = threadIdx.x;
  double a = 0.0;
  for (int n = t; n < NN; n += 256) a += Q[(size_t)n*RK + j];
  __shared__ double sh[256];
  sh[t] = a; __syncthreads();
  for (int off = 128; off > 0; off >>= 1){ if (t < off) sh[t] += sh[t+off]; __syncthreads(); }
  if (t == 0) qs[j] = sh[0];
}
__global__ __launch_bounds__(256) void k_deg2f(const double* __restrict__ C, const double* __restrict__ qs,
                                               float* __restrict__ dinv2){
  int i = blockIdx.x*256 + threadIdx.x;
  if (i >= NN) return;
  double s = 0.0;
  #pragma unroll
  for (int k = 0; k < RK; k++) s += C[(size_t)i*RK + k] * qs[k];
  dinv2[i] = (s > 0.0) ? (float)(1.0/sqrt(s)) : 0.f;
}

// ---------------- SpMM over sorted edge lists (f32, branch 1) ----------------
__global__ void k_spmm(const int* __restrict__ ptr, const int* __restrict__ eid,
                       const int* __restrict__ oidx, const float* __restrict__ coef,
                       const float* __restrict__ X, int ldx,
                       float* __restrict__ Y, int ldy, int F,
                       const float* __restrict__ self_dinv, const float* __restrict__ bias){
  int seg = blockIdx.x;
  int t = threadIdx.x, bd = blockDim.x;
  int f1 = t + bd;
  bool two = (f1 < F);
  float acc0 = 0.f, acc1 = 0.f;
  if (self_dinv){
    float sd = self_dinv[seg]; float s2 = sd*sd;
    acc0 = s2 * X[(size_t)seg*ldx + t];
    if (two) acc1 = s2 * X[(size_t)seg*ldx + f1];
  }
  int p0 = ptr[seg], p1 = ptr[seg+1];
  for (int p = p0; p < p1; ++p){
    int e = eid[p];
    int o = oidx[e];
    float c = coef[e];
    const float* xr = X + (size_t)o*ldx;
    acc0 += c * xr[t];
    if (two) acc1 += c * xr[f1];
  }
  if (bias){ acc0 += bias[t]; if (two) acc1 += bias[f1]; }
  Y[(size_t)seg*ldy + t] = acc0;
  if (two) Y[(size_t)seg*ldy + f1] = acc1;
}

// ---------------- domain-specific BN ----------------
__global__ __launch_bounds__(256) void k_bnstats(const float* __restrict__ H, const int* __restrict__ y,
        const int* __restrict__ dcnt, const float* __restrict__ gamma, const float* __restrict__ beta,
        float* __restrict__ scal, float* __restrict__ shft){
  int j = blockIdx.x;
  int t = threadIdx.x;
  float s0=0,s1=0,s2=0,s3=0,q0=0,q1=0,q2=0,q3=0;
  for (int n = t; n < NN; n += 256){
    float v = H[(size_t)n*HIDC + j];
    int d = y[n];
    float v2 = v*v;
    if      (d == 0){ s0 += v; q0 += v2; }
    else if (d == 1){ s1 += v; q1 += v2; }
    else if (d == 2){ s2 += v; q2 += v2; }
    else            { s3 += v; q3 += v2; }
  }
  __shared__ float sh[256][8];
  sh[t][0]=s0; sh[t][1]=s1; sh[t][2]=s2; sh[t][3]=s3;
  sh[t][4]=q0; sh[t][5]=q1; sh[t][6]=q2; sh[t][7]=q3;
  __syncthreads();
  for (int off = 128; off > 0; off >>= 1){
    if (t < off){
      #pragma unroll
      for (int q = 0; q < 8; q++) sh[t][q] += sh[t+off][q];
    }
    __syncthreads();
  }
  if (t < NDOM){
    float cnt  = fmaxf((float)dcnt[t], 1.0f);
    float mean = sh[0][t] / cnt;
    float var  = fmaxf(sh[0][4+t] / cnt - mean*mean, 0.f);
    float inv  = 1.0f / sqrtf(var + EPSBN);
    float gmm  = gamma[t*HIDC + j];
    scal[t*HIDC + j] = gmm * inv;
    shft[t*HIDC + j] = beta[t*HIDC + j] - mean * gmm * inv;
  }
}
__global__ __launch_bounds__(256) void k_bnapply(float* __restrict__ H, const int* __restrict__ y,
        const float* __restrict__ scal, const float* __restrict__ shft){
  int idx = blockIdx.x*256 + threadIdx.x;
  if (idx >= NN*HIDC) return;
  int n = idx >> 9, j = idx & (HIDC-1);
  int d = y[n];
  float v = H[idx] * scal[d*HIDC + j] + shft[d*HIDC + j];
  H[idx] = v > 0.f ? v : 0.f;
}

// ---------------- launch ----------------
extern "C" void kernel_launch(void* const* d_in, const int* in_sizes, int n_in,
                              void* d_out, int out_size, void* d_ws, size_t ws_size,
                              hipStream_t stream){
  (void)in_sizes; (void)n_in; (void)out_size;
  const void* x_in  = d_in[0];
  const int*  ei    = (const int*)d_in[1];
  const void* w_in  = d_in[2];
  const int*  yv    = (const int*)d_in[3];
  const void* W1i   = d_in[4];
  const void* b1i   = d_in[5];
  const void* Wmui  = d_in[6];
  const void* bmui  = d_in[7];
  const void* Wlvi  = d_in[8];
  const void* blvi  = d_in[9];
  const void* gmi   = d_in[10];
  const void* bti   = d_in[11];
  const int* rowA = ei;
  const int* colA = ei + NEDG;

  // ---- workspace: doubles | floats | ints (~38 MB) ----
  double* Dp = (double*)d_ws;
  size_t od = 0;
  double* Qd0 = Dp + od; od += (size_t)NN*RK;
  double* Qd1 = Dp + od; od += (size_t)NN*RK;
  double* Cd  = Dp + od; od += (size_t)NN*RK;
  double* Gd  = Dp + od; od += RK*RK;
  double* Rid = Dp + od; od += RK*RK;
  double* qsd = Dp + od; od += RK;
  float* Fp = (float*)(Dp + od);
  size_t o = 0;
  float* xf   = Fp + o; o += (size_t)NN*INC;       // reused as h1/h2 buffer
  float* W1f  = Fp + o; o += (size_t)INC*HIDC;
  float* b1f  = Fp + o; o += HIDC;
  float* Wmuf = Fp + o; o += (size_t)HIDC*OUTC;
  float* bmuf = Fp + o; o += OUTC;
  float* Wlvf = Fp + o; o += (size_t)HIDC*OUTC;
  float* blvf = Fp + o; o += OUTC;
  float* gmf  = Fp + o; o += NDOM*HIDC;
  float* btf  = Fp + o; o += NDOM*HIDC;
  float* wf   = Fp + o; o += NEDG;
  float* xw1  = Fp + o; o += (size_t)NN*HIDC;
  float* hwA  = Fp + o; o += (size_t)NN*OUTC;
  float* hwB  = Fp + o; o += (size_t)NN*OUTC;     // contiguous after hwA
  float* Bf0  = Fp + o; o += (size_t)NN*RK;        // omega (f32)
  float* Bf1  = Fp + o; o += (size_t)NN*RK;        // Qb (f32)
  float* Cm   = Fp + o; o += (size_t)NN*RK;        // C (f32)
  float* Tm   = Fp + o; o += (size_t)RK*HIDC;
  float* Umu  = Fp + o; o += RK*RK;
  float* deg1 = Fp + o; o += NN;
  float* dinv1= Fp + o; o += NN;
  float* dinv2= Fp + o; o += NN;
  float* norm1= Fp + o; o += NEDG;
  float* scal = Fp + o; o += NDOM*HIDC;
  float* shft = Fp + o; o += NDOM*HIDC;
  float* zb   = Fp + o; o += (size_t)4*NN*OUTC;
  int* Ip = (int*)(Fp + o);
  size_t oi = 0;
  int* cntR = Ip + oi; oi += NN;
  int* ptrR = Ip + oi; oi += NN + 1;
  int* posR = Ip + oi; oi += NN;
  int* eidR = Ip + oi; oi += NEDG;
  int* cntC = Ip + oi; oi += NN;
  int* ptrC = Ip + oi; oi += NN + 1;
  int* posC = Ip + oi; oi += NN;
  int* eidC = Ip + oi; oi += NEDG;
  int* dcnt = Ip + oi; oi += NDOM;
  int* dflag= Ip + oi; oi += 1;

  size_t need = od*sizeof(double) + o*sizeof(float) + (oi+16)*sizeof(int);
  if (ws_size < need) return;

  float* hbuf = xf;  // x dead after xw1 GEMM

  const int T = 256;
  k_detect<<<1,T,0,stream>>>((const unsigned short*)x_in, dflag);
  k_upcast<<<cdiv(NN*INC,T),T,0,stream>>>(x_in, dflag, xf, NN*INC);
  k_upcast<<<cdiv(INC*HIDC,T),T,0,stream>>>(W1i, dflag, W1f, INC*HIDC);
  k_upcast<<<cdiv(HIDC,T),T,0,stream>>>(b1i, dflag, b1f, HIDC);
  k_upcast<<<cdiv(HIDC*OUTC,T),T,0,stream>>>(Wmui, dflag, Wmuf, HIDC*OUTC);
  k_upcast<<<1,T,0,stream>>>(bmui, dflag, bmuf, OUTC);
  k_upcast<<<cdiv(HIDC*OUTC,T),T,0,stream>>>(Wlvi, dflag, Wlvf, HIDC*OUTC);
  k_upcast<<<1,T,0,stream>>>(blvi, dflag, blvf, OUTC);
  k_upcast<<<cdiv(NDOM*HIDC,T),T,0,stream>>>(gmi, dflag, gmf, NDOM*HIDC);
  k_upcast<<<cdiv(NDOM*HIDC,T),T,0,stream>>>(bti, dflag, btf, NDOM*HIDC);
  k_upcast<<<cdiv(NEDG,T),T,0,stream>>>(w_in, dflag, wf, NEDG);

  k_fill <<<cdiv(NN,T),T,0,stream>>>(deg1, 1.0f, NN);   // self-loop weight 1
  k_filli<<<cdiv(NN,T),T,0,stream>>>(cntR, 0, NN);
  k_filli<<<cdiv(NN,T),T,0,stream>>>(cntC, 0, NN);
  k_filli<<<1,T,0,stream>>>(dcnt, 0, NDOM);
  k_hist <<<cdiv(NEDG,T),T,0,stream>>>(rowA, colA, wf, deg1, cntR, cntC);
  k_dinv <<<cdiv(NN,T),T,0,stream>>>(deg1, dinv1, NN);
  k_norm1<<<cdiv(NEDG,T),T,0,stream>>>(rowA, colA, wf, dinv1, norm1);
  k_scan4096<<<1,1024,0,stream>>>(cntR, ptrR, posR);
  k_scan4096<<<1,1024,0,stream>>>(cntC, ptrC, posC);
  k_scatter<<<cdiv(NEDG,T),T,0,stream>>>(rowA, colA, posR, posC, eidR, eidC);
  k_omega<<<cdiv(262144,T),T,0,stream>>>(Bf0);
  k_dcnt <<<cdiv(NN,T),T,0,stream>>>(yv, dcnt);

  // ---- branch 1 (verified) ----
  k_gemm_nn<<<dim3(HIDC/64, NN/64),256,0,stream>>>(NN,HIDC,INC, xf,INC, W1f,HIDC, xw1,HIDC, nullptr,nullptr,nullptr);
  k_spmm<<<NN,256,0,stream>>>(ptrC,eidC,rowA,norm1, xw1,HIDC, hbuf,HIDC, HIDC, dinv1, b1f);
  k_bnstats<<<HIDC,256,0,stream>>>(hbuf, yv, dcnt, gmf, btf, scal, shft);
  k_bnapply<<<cdiv(NN*HIDC,T),T,0,stream>>>(hbuf, yv, scal, shft);
  k_fill<<<cdiv(2*NN*OUTC,T),T,0,stream>>>(hwA, 0.f, 2*NN*OUTC);   // hwA|hwB contiguous
  k_gemm_nn_sk<<<dim3(1, NN/64, 4),256,0,stream>>>(NN,OUTC,HIDC,128, hbuf,HIDC, Wmuf,OUTC, hwA,OUTC);
  k_gemm_nn_sk<<<dim3(1, NN/64, 4),256,0,stream>>>(NN,OUTC,HIDC,128, hbuf,HIDC, Wlvf,OUTC, hwB,OUTC);
  k_spmm<<<NN,64,0,stream>>>(ptrC,eidC,rowA,norm1, hwA,OUTC, zb + 0*NN*OUTC,OUTC, OUTC, dinv1, bmuf);
  k_spmm<<<NN,64,0,stream>>>(ptrC,eidC,rowA,norm1, hwB,OUTC, zb + 1*NN*OUTC,OUTC, OUTC, dinv1, blvf);

  // ---- branch 2: f64 subspace (mid QR1 + final QR1), factored A2 ----
  auto spmmA64 = [&](const double* s, double* d){   // d = A @ s
    k_spmm64<<<NN,64,0,stream>>>(ptrR,eidR,colA,wf, s, d);
  };
  auto spmmAT64 = [&](const double* s, double* d){  // d = A^T @ s
    k_spmm64<<<NN,64,0,stream>>>(ptrC,eidC,rowA,wf, s, d);
  };
  auto orth164 = [&](double* src, double* dst){     // dst = src * R^{-1}
    k_filld<<<cdiv(RK*RK,T),T,0,stream>>>(Gd, 0.0, RK*RK);
    k_gram64<<<NN/64,256,0,stream>>>(src, Gd);
    k_cholinv64<<<1,256,0,stream>>>(Gd, Rid);
    k_applyR64<<<NN/4,256,0,stream>>>(src, Rid, dst);
  };

  k_f32to64<<<cdiv(NN*RK,T),T,0,stream>>>(Bf0, Qd0, NN*RK);
  spmmA64 (Qd0, Qd1);                      // P1 -> Qd1
  spmmAT64(Qd1, Qd0);                      // P2 -> Qd0
  spmmA64 (Qd0, Qd1);                      // P3 -> Qd1
  orth164(Qd1, Qd0);                       // mid QR1 -> Qd0 (range-exact)
  spmmAT64(Qd0, Qd1);                      // P4 -> Qd1
  spmmA64 (Qd1, Qd0);                      // P5 -> Qd0 (kappa ~ 25)
  orth164(Qd0, Qd1);                       // final QR1 -> Qb in Qd1 (orth ~6e-14)
  spmmAT64(Qd1, Cd);                       // C = A^T Qb  (A2 = Qb C^T)
  k_qsum64<<<RK,256,0,stream>>>(Qd1, qsd);
  k_deg2f<<<cdiv(NN,T),T,0,stream>>>(Cd, qsd, dinv2);
  k_f64to32<<<cdiv(NN*RK,T),T,0,stream>>>(Qd1, Bf1, NN*RK);
  k_f64to32<<<cdiv(NN*RK,T),T,0,stream>>>(Cd,  Cm,  NN*RK);

  // h2 = dsbn_relu( D C (Qb^T (D xw1)) + b1 )
  k_fill<<<cdiv(RK*HIDC,T),T,0,stream>>>(Tm, 0.f, RK*HIDC);
  k_gemm_tn_sk<<<dim3(HIDC/16, RK/16, 8),256,0,stream>>>(RK,HIDC,NN,512, Bf1,RK, xw1,HIDC, Tm,HIDC, dinv2);
  k_gemm_nn<<<dim3(HIDC/64, NN/64),256,0,stream>>>(NN,HIDC,RK, Cm,RK, Tm,HIDC, hbuf,HIDC, dinv2, nullptr, b1f);
  k_bnstats<<<HIDC,256,0,stream>>>(hbuf, yv, dcnt, gmf, btf, scal, shft);
  k_bnapply<<<cdiv(NN*HIDC,T),T,0,stream>>>(hbuf, yv, scal, shft);
  // z2 = D C (Qb^T (D (h2 W))) + b
  k_fill<<<cdiv(2*NN*OUTC,T),T,0,stream>>>(hwA, 0.f, 2*NN*OUTC);
  k_gemm_nn_sk<<<dim3(1, NN/64, 4),256,0,stream>>>(NN,OUTC,HIDC,128, hbuf,HIDC, Wmuf,OUTC, hwA,OUTC);
  k_gemm_nn_sk<<<dim3(1, NN/64, 4),256,0,stream>>>(NN,OUTC,HIDC,128, hbuf,HIDC, Wlvf,OUTC, hwB,OUTC);
  k_fill<<<cdiv(RK*RK,T),T,0,stream>>>(Umu, 0.f, RK*RK);
  k_gemm_tn_sk<<<dim3(RK/16, RK/16, 16),256,0,stream>>>(RK,RK,NN,256, Bf1,RK, hwA,OUTC, Umu,RK, dinv2);
  k_gemm_nn<<<dim3(1, NN/64),256,0,stream>>>(NN,OUTC,RK, Cm,RK, Umu,RK, zb + 2*NN*OUTC,OUTC, dinv2, nullptr, bmuf);
  k_fill<<<cdiv(RK*RK,T),T,0,stream>>>(Umu, 0.f, RK*RK);
  k_gemm_tn_sk<<<dim3(RK/16, RK/16, 16),256,0,stream>>>(RK,RK,NN,256, Bf1,RK, hwB,OUTC, Umu,RK, dinv2);
  k_gemm_nn<<<dim3(1, NN/64),256,0,stream>>>(NN,OUTC,RK, Cm,RK, Umu,RK, zb + 3*NN*OUTC,OUTC, dinv2, nullptr, blvf);

  // outputs -> f32
  k_copy<<<cdiv(4*NN*OUTC,T),T,0,stream>>>(zb, (float*)d_out, 4*NN*OUTC);
}